// Round 2
// baseline (1420.078 us; speedup 1.0000x reference)
//
#include <hip/hip_runtime.h>
#include <cmath>

#define B_  128
#define T_  512
#define E_  128
#define H_  128
#define G4  512   // 4*H
#define K_  9

// ---------------------------------------------------------------------------
// Kernel 1 (v2): input projection, register-resident weights, zero LDS.
// Lane owns gate-row nrow = (ngrp&7)*64 + lane of direction ngrp>>3, holding
// W[nrow][0:128] in 128 VGPRs. The embed row for each (b,t) is wave-uniform
// (vid via readfirstlane) -> scalar/broadcast loads feed v_fma as the SGPR
// operand. Per m-row: 8 uniform float4 loads + 128 FMA + 1 coalesced store.
// No ds_read, no barriers -> pure VALU-bound (fp32 floor ~109 us chip-wide).
// ---------------------------------------------------------------------------
__global__ __launch_bounds__(256, 2)
void proj_gemm2(const int* __restrict__ sent, const float* __restrict__ embed,
                const float* __restrict__ Wf, const float* __restrict__ Wb,
                const float* __restrict__ bif, const float* __restrict__ bhf,
                const float* __restrict__ bib, const float* __restrict__ bhb,
                float* __restrict__ proj, int t0f, int Tc, int tcshift,
                int rows_per_block)
{
  const int lane = threadIdx.x & 63;
  const int wv   = __builtin_amdgcn_readfirstlane((int)(threadIdx.x >> 6));
  const int ngrp = __builtin_amdgcn_readfirstlane((int)(blockIdx.x * 4 + wv)); // 0..15
  const int dir  = ngrp >> 3;
  const int nsub = (ngrp & 7) << 6;          // 0..448
  const int nrow = nsub + lane;              // gate row 0..511
  const float* __restrict__ W = dir ? Wb : Wf;
  const float* bi = dir ? bib : bif;
  const float* bh = dir ? bhb : bhf;

  float w[128];
#pragma unroll
  for (int k = 0; k < 128; k += 4) {
    float4 v = *(const float4*)(W + (size_t)nrow * E_ + k);
    w[k] = v.x; w[k + 1] = v.y; w[k + 2] = v.z; w[k + 3] = v.w;
  }
  const float bias = bi[nrow] + bh[nrow];

  const int t0  = dir ? (T_ - t0f - Tc) : t0f;
  const int tcm = Tc - 1;
  const int r0  = blockIdx.y * rows_per_block;

  for (int r = r0; r < r0 + rows_per_block; r += 2) {
    // two rows in flight: uniform scalar-load chains overlap the FMA streams
    const int ba = r >> tcshift,        bb2 = (r + 1) >> tcshift;
    const int ta = t0 + (r & tcm),      tb  = t0 + ((r + 1) & tcm);
    const int va = __builtin_amdgcn_readfirstlane(sent[ba * T_ + ta]);
    const int vb = __builtin_amdgcn_readfirstlane(sent[bb2 * T_ + tb]);
    const float4* ea = (const float4*)(embed + (size_t)va * E_);
    const float4* eb = (const float4*)(embed + (size_t)vb * E_);

    float pa0 = 0.f, pa1 = 0.f, pa2 = 0.f, pa3 = 0.f;
    float pb0 = 0.f, pb1 = 0.f, pb2 = 0.f, pb3 = 0.f;
#pragma unroll
    for (int q = 0; q < 32; q += 4) {
      float4 xa0 = ea[q + 0], xa1 = ea[q + 1], xa2 = ea[q + 2], xa3 = ea[q + 3];
      float4 xb0 = eb[q + 0], xb1 = eb[q + 1], xb2 = eb[q + 2], xb3 = eb[q + 3];
      const int k = 4 * q;
      pa0 += w[k + 0] * xa0.x;  pa0 += w[k + 1] * xa0.y;
      pa0 += w[k + 2] * xa0.z;  pa0 += w[k + 3] * xa0.w;
      pb0 += w[k + 0] * xb0.x;  pb0 += w[k + 1] * xb0.y;
      pb0 += w[k + 2] * xb0.z;  pb0 += w[k + 3] * xb0.w;
      pa1 += w[k + 4] * xa1.x;  pa1 += w[k + 5] * xa1.y;
      pa1 += w[k + 6] * xa1.z;  pa1 += w[k + 7] * xa1.w;
      pb1 += w[k + 4] * xb1.x;  pb1 += w[k + 5] * xb1.y;
      pb1 += w[k + 6] * xb1.z;  pb1 += w[k + 7] * xb1.w;
      pa2 += w[k + 8] * xa2.x;  pa2 += w[k + 9] * xa2.y;
      pa2 += w[k +10] * xa2.z;  pa2 += w[k +11] * xa2.w;
      pb2 += w[k + 8] * xb2.x;  pb2 += w[k + 9] * xb2.y;
      pb2 += w[k +10] * xb2.z;  pb2 += w[k +11] * xb2.w;
      pa3 += w[k +12] * xa3.x;  pa3 += w[k +13] * xa3.y;
      pa3 += w[k +14] * xa3.z;  pa3 += w[k +15] * xa3.w;
      pb3 += w[k +12] * xb3.x;  pb3 += w[k +13] * xb3.y;
      pb3 += w[k +14] * xb3.z;  pb3 += w[k +15] * xb3.w;
    }
    const float sa = ((pa0 + pa1) + (pa2 + pa3)) + bias;
    const float sb = ((pb0 + pb1) + (pb2 + pb3)) + bias;
    proj[(size_t)r       * 1024 + dir * G4 + nsub + lane] = sa;
    proj[(size_t)(r + 1) * 1024 + dir * G4 + nsub + lane] = sb;
  }
}

// ---------------------------------------------------------------------------
// Kernel 2: LSTM recurrence, one block per (direction, batch element).
// 512 threads: thread g owns gate row g (Whh[g][:] in 128 VGPRs).
// h lives in LDS (broadcast reads); c in registers of threads 0..127.
// Packed-sequence semantics: state frozen + output zeroed where t >= len.
// ---------------------------------------------------------------------------
__global__ __launch_bounds__(512, 2)
void lstm_chunk(const float* __restrict__ proj,
                const float* __restrict__ Whf, const float* __restrict__ Whb,
                const int* __restrict__ lengths,
                float* __restrict__ hs,
                float* __restrict__ sh, float* __restrict__ sc,
                int t0f, int Tc, int first)
{
  const int dir = blockIdx.x;
  const int b   = blockIdx.y;
  const int tid = threadIdx.x;
  const float* __restrict__ Whh = dir ? Whb : Whf;
  __shared__ __align__(16) float h_lds[H_];
  __shared__ float gates[G4];

  float w[128];
  {
    const float* wr = Whh + (size_t)tid * H_;
#pragma unroll
    for (int k = 0; k < 128; k += 4) {
      float4 v = *(const float4*)(wr + k);
      w[k] = v.x; w[k + 1] = v.y; w[k + 2] = v.z; w[k + 3] = v.w;
    }
  }
  const int len = lengths[b];
  const int t0  = dir ? (T_ - t0f - Tc) : t0f;
  float c = 0.f;
  if (tid < H_) {
    if (first) {
      h_lds[tid] = 0.f;
    } else {
      h_lds[tid] = sh[(dir * B_ + b) * H_ + tid];
      c          = sc[(dir * B_ + b) * H_ + tid];
    }
  }
  __syncthreads();

  const float* projp = proj + (size_t)b * Tc * 1024 + dir * G4 + tid;
  for (int s = 0; s < Tc; ++s) {
    const int tc = dir ? (Tc - 1 - s) : s;   // backward scans t descending
    const int t  = t0 + tc;
    float acc = projp[(size_t)tc * 1024];    // x@Wih^T + bih + bhh (precomputed)
#pragma unroll
    for (int k4 = 0; k4 < 32; ++k4) {
      float4 h4 = *(const float4*)&h_lds[k4 * 4];
      acc += w[4 * k4 + 0] * h4.x; acc += w[4 * k4 + 1] * h4.y;
      acc += w[4 * k4 + 2] * h4.z; acc += w[4 * k4 + 3] * h4.w;
    }
    const int blk = tid >> 7;                // 0:i 1:f 2:g 3:o (torch order)
    gates[tid] = (blk == 2) ? tanhf(acc) : 1.f / (1.f + expf(-acc));
    __syncthreads();
    if (tid < H_) {
      float gi = gates[tid], gf = gates[tid + 128];
      float gg = gates[tid + 256], go = gates[tid + 384];
      float cn = gf * c + gi * gg;
      float hn = go * tanhf(cn);
      bool  m  = (t < len);
      float hold = h_lds[tid];
      c = m ? cn : c;
      h_lds[tid] = m ? hn : hold;
      hs[(size_t)(b * T_ + t) * 256 + dir * H_ + tid] = m ? hn : 0.f;
    }
    __syncthreads();
  }
  if (tid < H_) {
    sh[(dir * B_ + b) * H_ + tid] = h_lds[tid];
    sc[(dir * B_ + b) * H_ + tid] = c;
  }
}

// ---------------------------------------------------------------------------
// Kernel 3: emissions em[m][k] = hs[m][:] . W_out[k][:] + b_out[k]
// ---------------------------------------------------------------------------
__global__ __launch_bounds__(256)
void emis_kernel(const float* __restrict__ hs, const float* __restrict__ Wout,
                 const float* __restrict__ bout, float* __restrict__ em)
{
  __shared__ __align__(16) float Wl[K_ * 256];
  const int tid = threadIdx.x;
  for (int i = tid; i < K_ * 256; i += 256) Wl[i] = Wout[i];
  __syncthreads();
  const int m = blockIdx.x * 256 + tid;
  const float* h = hs + (size_t)m * 256;
  float acc[K_] = {};
#pragma unroll 4
  for (int kk = 0; kk < 64; ++kk) {
    float4 h4 = *(const float4*)(h + kk * 4);
#pragma unroll
    for (int k9 = 0; k9 < K_; ++k9) {
      float4 w4 = *(const float4*)&Wl[k9 * 256 + kk * 4];
      acc[k9] += h4.x * w4.x + h4.y * w4.y + h4.z * w4.z + h4.w * w4.w;
    }
  }
#pragma unroll
  for (int k9 = 0; k9 < K_; ++k9) em[(size_t)m * K_ + k9] = acc[k9] + bout[k9];
}

// ---------------------------------------------------------------------------
// Kernel 4: Viterbi decode, one 64-lane wave per batch element.
// ---------------------------------------------------------------------------
__global__ __launch_bounds__(64)
void viterbi_kernel(const float* __restrict__ em, const int* __restrict__ lengths,
                    const float* __restrict__ st, const float* __restrict__ en,
                    const float* __restrict__ trans, int* __restrict__ tags)
{
  const int b    = blockIdx.x;
  const int lane = threadIdx.x;
  __shared__ unsigned char hist[(T_ - 1) * 16];
  const int len = lengths[b];
  float tr[K_];
#pragma unroll
  for (int j = 0; j < K_; ++j) tr[j] = (lane < K_) ? trans[j * K_ + lane] : 0.f;
  float s = (lane < K_) ? st[lane] + em[(size_t)(b * T_) * K_ + lane] : -1e30f;
  for (int t = 1; t < len; ++t) {
    float best = -1e30f; int bj = 0;
#pragma unroll
    for (int j = 0; j < K_; ++j) {
      float v = __shfl(s, j) + tr[j];
      if (v > best) { best = v; bj = j; }    // strict > == first-max (argmax)
    }
    if (lane < K_) {
      s = best + em[(size_t)(b * T_ + t) * K_ + lane];
      hist[(t - 1) * 16 + lane] = (unsigned char)bj;
    }
  }
  float fs = (lane < K_) ? s + en[lane] : -1e30f;
  float best = -1e30f; int last = 0;
#pragma unroll
  for (int j = 0; j < K_; ++j) {
    float v = __shfl(fs, j);
    if (v > best) { best = v; last = j; }
  }
  __syncthreads();                            // hist visible to lane 0
  if (lane == 0) {
    int tag = last;
    tags[b * T_ + len - 1] = tag;
    for (int t = len - 2; t >= 0; --t) {
      tag = hist[t * 16 + tag];
      tags[b * T_ + t] = tag;
    }
  }
  for (int t = len + lane; t < T_; t += 64) tags[b * T_ + t] = 0;
}

// ---------------------------------------------------------------------------
extern "C" void kernel_launch(void* const* d_in, const int* in_sizes, int n_in,
                              void* d_out, int out_size, void* d_ws, size_t ws_size,
                              hipStream_t stream)
{
  const int*   sent  = (const int*)d_in[0];
  const int*   lens  = (const int*)d_in[1];
  const float* embed = (const float*)d_in[2];
  const float* Wif   = (const float*)d_in[3];
  const float* Whf   = (const float*)d_in[4];
  const float* bif   = (const float*)d_in[5];
  const float* bhf   = (const float*)d_in[6];
  const float* Wib   = (const float*)d_in[7];
  const float* Whb   = (const float*)d_in[8];
  const float* bib   = (const float*)d_in[9];
  const float* bhb   = (const float*)d_in[10];
  const float* Wout  = (const float*)d_in[11];
  const float* bout  = (const float*)d_in[12];
  const float* stt   = (const float*)d_in[13];
  const float* ent   = (const float*)d_in[14];
  const float* trans = (const float*)d_in[15];
  int* tags = (int*)d_out;

  // workspace layout (floats): hs | em | state_h | state_c | proj(chunked)
  float* ws   = (float*)d_ws;
  float* hs   = ws;                                  // B*T*256   (67.1 MB)
  float* em   = hs + (size_t)B_ * T_ * 256;          // B*T*9     ( 2.4 MB)
  float* sh   = em + (size_t)B_ * T_ * K_;           // 2*B*H carry h
  float* sc   = sh + (size_t)2 * B_ * H_;            // 2*B*H carry c
  float* proj = sc + (size_t)2 * B_ * H_;
  const size_t fixed_bytes = (size_t)(proj - ws) * sizeof(float);

  // largest time-chunk whose proj buffer fits the workspace (floor at 64)
  int Tc = 512, tcshift = 9;
  while (Tc > 64 && fixed_bytes + (size_t)B_ * Tc * 1024 * sizeof(float) > ws_size) {
    Tc >>= 1; tcshift--;
  }

  const int nch = T_ / Tc;
  for (int c2 = 0; c2 < nch; ++c2) {
    const int t0f = c2 * Tc;
    const int rows = B_ * Tc;                 // m-rows this chunk
    const int rpb  = rows / 256;              // rows per block (even, >=32)
    dim3 g1(4, 256);
    hipLaunchKernelGGL(proj_gemm2, g1, dim3(256), 0, stream,
                       sent, embed, Wif, Wib, bif, bhf, bib, bhb,
                       proj, t0f, Tc, tcshift, rpb);
    dim3 g2(2, B_);
    hipLaunchKernelGGL(lstm_chunk, g2, dim3(512), 0, stream,
                       proj, Whf, Whb, lens, hs, sh, sc, t0f, Tc, (int)(c2 == 0));
  }
  hipLaunchKernelGGL(emis_kernel, dim3((B_ * T_) / 256), dim3(256), 0, stream,
                     hs, Wout, bout, em);
  hipLaunchKernelGGL(viterbi_kernel, dim3(B_), dim3(64), 0, stream,
                     em, lens, stt, ent, trans, tags);
}

// Round 3
// 1198.506 us; speedup vs baseline: 1.1849x; 1.1849x over previous
//
#include <hip/hip_runtime.h>
#include <cmath>

#define B_  128
#define T_  512
#define E_  128
#define H_  128
#define G4  512   // 4*H
#define K_  9
#define PADK 136  // 128 + 8 pad (keeps 16B alignment: 136*2B = 272 = 17*16)

typedef __attribute__((ext_vector_type(8))) short  short8;
typedef __attribute__((ext_vector_type(4))) float  f32x4;

__device__ __forceinline__ unsigned short bf16_rnd(float x) {
  return (unsigned short)((__float_as_uint(x) + 0x8000u) >> 16);
}
__device__ __forceinline__ float bf16_val(unsigned short b) {
  return __uint_as_float(((unsigned int)b) << 16);
}

// ---------------------------------------------------------------------------
// Kernel 1 (v3): split-bf16 MFMA projection GEMM with fused embed gather.
// C = A_emb . W^T computed as hi*hi + hi*lo + lo*hi (lo*lo dropped, ~2e-6 rel).
// Tile 64(M) x 64(N) x 128(K full). 4 waves; wave w owns m-rows [16w,16w+16).
// A and W are both [row][k] row-major -> identical b128 fragment loads (m97
// B^T pattern). C/D layout: col=lane&15, row=(lane>>4)*4+reg (m89-verified).
// ---------------------------------------------------------------------------
__global__ __launch_bounds__(256, 2)
void proj_mfma(const int* __restrict__ sent, const float* __restrict__ embed,
               const float* __restrict__ Wf, const float* __restrict__ Wb,
               const float* __restrict__ bif, const float* __restrict__ bhf,
               const float* __restrict__ bib, const float* __restrict__ bhb,
               float* __restrict__ proj, int t0f, int Tc, int tcshift)
{
  __shared__ unsigned short As[2 * 64 * PADK];  // plane 0 = hi, 1 = lo
  __shared__ unsigned short Bs[2 * 64 * PADK];
  const int tid   = threadIdx.x;
  const int ntile = blockIdx.x;            // 0..15
  const int dir   = ntile >> 3;
  const int n0    = (ntile & 7) << 6;      // 0..448
  const int m0    = blockIdx.y << 6;       // chunk-local row base
  const float* __restrict__ W = dir ? Wb : Wf;
  const int t0  = dir ? (T_ - t0f - Tc) : t0f;
  const int tcm = Tc - 1;

  // ---- stage: 4 threads per row, each converts 32 fp32 -> hi/lo bf16
  {
    const int r   = tid >> 2;              // 0..63
    const int seg = (tid & 3) << 5;        // 0,32,64,96
    const int rr  = m0 + r;
    const int b   = rr >> tcshift;
    const int t   = t0 + (rr & tcm);
    const int vid = sent[b * T_ + t];
    const float* arow = embed + (size_t)vid * E_ + seg;
    const float* brow = W + (size_t)(n0 + r) * E_ + seg;
    unsigned short* ah = As + r * PADK + seg;
    unsigned short* al = ah + 64 * PADK;
    unsigned short* bh = Bs + r * PADK + seg;
    unsigned short* bl = bh + 64 * PADK;
#pragma unroll
    for (int q = 0; q < 32; q += 4) {
      float4 av = *(const float4*)(arow + q);
      float4 bv = *(const float4*)(brow + q);
      ushort4 vh, vl;
      vh.x = bf16_rnd(av.x); vl.x = bf16_rnd(av.x - bf16_val(vh.x));
      vh.y = bf16_rnd(av.y); vl.y = bf16_rnd(av.y - bf16_val(vh.y));
      vh.z = bf16_rnd(av.z); vl.z = bf16_rnd(av.z - bf16_val(vh.z));
      vh.w = bf16_rnd(av.w); vl.w = bf16_rnd(av.w - bf16_val(vh.w));
      *(ushort4*)(ah + q) = vh; *(ushort4*)(al + q) = vl;
      vh.x = bf16_rnd(bv.x); vl.x = bf16_rnd(bv.x - bf16_val(vh.x));
      vh.y = bf16_rnd(bv.y); vl.y = bf16_rnd(bv.y - bf16_val(vh.y));
      vh.z = bf16_rnd(bv.z); vl.z = bf16_rnd(bv.z - bf16_val(vh.z));
      vh.w = bf16_rnd(bv.w); vl.w = bf16_rnd(bv.w - bf16_val(vh.w));
      *(ushort4*)(bh + q) = vh; *(ushort4*)(bl + q) = vl;
    }
  }
  __syncthreads();

  const int lane = tid & 63;
  const int wv   = tid >> 6;
  const int frow = lane & 15;              // fragment row (m for A, n for B)
  const int kq   = (lane >> 4) << 3;       // k sub-offset 0,8,16,24
  const unsigned short* Abase = As + (wv * 16 + frow) * PADK + kq;
  const unsigned short* Bbase = Bs + frow * PADK + kq;
  f32x4 acc[4] = {};

#pragma unroll
  for (int kf = 0; kf < 4; ++kf) {
    short8 ah = *(const short8*)(Abase + kf * 32);
    short8 al = *(const short8*)(Abase + 64 * PADK + kf * 32);
    short8 bh[4], bl[4];
#pragma unroll
    for (int nf = 0; nf < 4; ++nf) {
      bh[nf] = *(const short8*)(Bbase + nf * 16 * PADK + kf * 32);
      bl[nf] = *(const short8*)(Bbase + (64 + nf * 16) * PADK + kf * 32);
    }
#pragma unroll
    for (int nf = 0; nf < 4; ++nf)
      acc[nf] = __builtin_amdgcn_mfma_f32_16x16x32_bf16(ah, bh[nf], acc[nf], 0, 0, 0);
#pragma unroll
    for (int nf = 0; nf < 4; ++nf)
      acc[nf] = __builtin_amdgcn_mfma_f32_16x16x32_bf16(ah, bl[nf], acc[nf], 0, 0, 0);
#pragma unroll
    for (int nf = 0; nf < 4; ++nf)
      acc[nf] = __builtin_amdgcn_mfma_f32_16x16x32_bf16(al, bh[nf], acc[nf], 0, 0, 0);
  }

  const float* bi  = dir ? bib : bif;
  const float* bh2 = dir ? bhb : bhf;
  const int coln = n0 + (lane & 15);
  const int rowb = m0 + wv * 16 + ((lane >> 4) << 2);
#pragma unroll
  for (int nf = 0; nf < 4; ++nf) {
    const int n = coln + nf * 16;
    const float bias = bi[n] + bh2[n];
#pragma unroll
    for (int rg = 0; rg < 4; ++rg)
      proj[(size_t)(rowb + rg) * 1024 + dir * G4 + n] = acc[nf][rg] + bias;
  }
}

// ---------------------------------------------------------------------------
// Kernel 2 (v2): LSTM recurrence, readlane h-broadcast (zero DS in hot loop).
// 256 threads; thread t owns gate rows t (i/f -> sigmoid) and t+256 (g/o).
// Each wave keeps a full copy of h as 2 VGPRs/lane; h[j] broadcast to all
// lanes via v_readlane -> SGPR operand of v_fmac (no ds_read storm).
// Whh rows (256 floats) register-resident: launch_bounds(256,1) allows 512.
// ---------------------------------------------------------------------------
__global__ __launch_bounds__(256, 1)
void lstm_chunk2(const float* __restrict__ proj,
                 const float* __restrict__ Whf, const float* __restrict__ Whb,
                 const int* __restrict__ lengths,
                 float* __restrict__ hs,
                 float* __restrict__ sh, float* __restrict__ sc,
                 int t0f, int Tc, int first)
{
  const int dir  = blockIdx.x;
  const int b    = blockIdx.y;
  const int tid  = threadIdx.x;            // 0..255
  const int lane = tid & 63;
  const float* __restrict__ Whh = dir ? Whb : Whf;
  __shared__ float h_lds[H_];
  __shared__ float gates[G4];

  float w0[128], w1[128];
  {
    const float* r0 = Whh + (size_t)tid * H_;
    const float* r1 = Whh + (size_t)(tid + 256) * H_;
#pragma unroll
    for (int k = 0; k < 128; k += 4) {
      float4 v0 = *(const float4*)(r0 + k);
      float4 v1 = *(const float4*)(r1 + k);
      w0[k] = v0.x; w0[k+1] = v0.y; w0[k+2] = v0.z; w0[k+3] = v0.w;
      w1[k] = v1.x; w1[k+1] = v1.y; w1[k+2] = v1.z; w1[k+3] = v1.w;
    }
  }
  const int len = lengths[b];
  const int t0  = dir ? (T_ - t0f - Tc) : t0f;
  float c = 0.f, hval = 0.f;
  if (tid < H_) {
    if (!first) {
      hval = sh[(dir * B_ + b) * H_ + tid];
      c    = sc[(dir * B_ + b) * H_ + tid];
    }
    h_lds[tid] = hval;
  }
  __syncthreads();
  float h0 = h_lds[lane], h1 = h_lds[lane + 64];

  const float* p0 = proj + (size_t)b * Tc * 1024 + dir * G4 + tid;
  const float* p1 = p0 + 256;
  const int stp = dir ? -1 : 1;
  int tc = dir ? (Tc - 1) : 0;
  float f0 = p0[(size_t)tc * 1024], f1 = p1[(size_t)tc * 1024];

  for (int s = 0; s < Tc; ++s) {
    const int t = t0 + tc;
    float acc0 = f0, acc1 = f1;
    int tcn = tc + stp;
    int tcl = tcn < 0 ? 0 : (tcn > Tc - 1 ? Tc - 1 : tcn);   // prefetch next
    f0 = p0[(size_t)tcl * 1024]; f1 = p1[(size_t)tcl * 1024];
#pragma unroll
    for (int j = 0; j < 64; ++j) {
      const float sj = __uint_as_float(__builtin_amdgcn_readlane(__float_as_uint(h0), j));
      acc0 += sj * w0[j]; acc1 += sj * w1[j];
    }
#pragma unroll
    for (int j = 0; j < 64; ++j) {
      const float sj = __uint_as_float(__builtin_amdgcn_readlane(__float_as_uint(h1), j));
      acc0 += sj * w0[64 + j]; acc1 += sj * w1[64 + j];
    }
    gates[tid]       = 1.f / (1.f + expf(-acc0));                          // i or f
    gates[tid + 256] = (tid < 128) ? tanhf(acc1) : 1.f / (1.f + expf(-acc1)); // g or o
    __syncthreads();
    if (tid < H_) {
      float gi = gates[tid], gf = gates[tid + 128];
      float gg = gates[tid + 256], go = gates[tid + 384];
      float cn = gf * c + gi * gg;
      float hn = go * tanhf(cn);
      bool  m  = (t < len);
      c    = m ? cn : c;
      hval = m ? hn : hval;
      h_lds[tid] = hval;
      hs[(size_t)(b * T_ + t) * 256 + dir * H_ + tid] = m ? hn : 0.f;
    }
    __syncthreads();
    h0 = h_lds[lane]; h1 = h_lds[lane + 64];
    tc = tcn;
  }
  if (tid < H_) {
    sh[(dir * B_ + b) * H_ + tid] = hval;
    sc[(dir * B_ + b) * H_ + tid] = c;
  }
}

// ---------------------------------------------------------------------------
// Kernel 3: emissions em[m][k] = hs[m][:] . W_out[k][:] + b_out[k]
// ---------------------------------------------------------------------------
__global__ __launch_bounds__(256)
void emis_kernel(const float* __restrict__ hs, const float* __restrict__ Wout,
                 const float* __restrict__ bout, float* __restrict__ em)
{
  __shared__ __align__(16) float Wl[K_ * 256];
  const int tid = threadIdx.x;
  for (int i = tid; i < K_ * 256; i += 256) Wl[i] = Wout[i];
  __syncthreads();
  const int m = blockIdx.x * 256 + tid;
  const float* h = hs + (size_t)m * 256;
  float acc[K_] = {};
#pragma unroll 4
  for (int kk = 0; kk < 64; ++kk) {
    float4 h4 = *(const float4*)(h + kk * 4);
#pragma unroll
    for (int k9 = 0; k9 < K_; ++k9) {
      float4 w4 = *(const float4*)&Wl[k9 * 256 + kk * 4];
      acc[k9] += h4.x * w4.x + h4.y * w4.y + h4.z * w4.z + h4.w * w4.w;
    }
  }
#pragma unroll
  for (int k9 = 0; k9 < K_; ++k9) em[(size_t)m * K_ + k9] = acc[k9] + bout[k9];
}

// ---------------------------------------------------------------------------
// Kernel 4: Viterbi decode, one 64-lane wave per batch element.
// ---------------------------------------------------------------------------
__global__ __launch_bounds__(64)
void viterbi_kernel(const float* __restrict__ em, const int* __restrict__ lengths,
                    const float* __restrict__ st, const float* __restrict__ en,
                    const float* __restrict__ trans, int* __restrict__ tags)
{
  const int b    = blockIdx.x;
  const int lane = threadIdx.x;
  __shared__ unsigned char hist[(T_ - 1) * 16];
  const int len = lengths[b];
  float tr[K_];
#pragma unroll
  for (int j = 0; j < K_; ++j) tr[j] = (lane < K_) ? trans[j * K_ + lane] : 0.f;
  float s = (lane < K_) ? st[lane] + em[(size_t)(b * T_) * K_ + lane] : -1e30f;
  for (int t = 1; t < len; ++t) {
    float best = -1e30f; int bj = 0;
#pragma unroll
    for (int j = 0; j < K_; ++j) {
      float v = __shfl(s, j) + tr[j];
      if (v > best) { best = v; bj = j; }    // strict > == first-max (argmax)
    }
    if (lane < K_) {
      s = best + em[(size_t)(b * T_ + t) * K_ + lane];
      hist[(t - 1) * 16 + lane] = (unsigned char)bj;
    }
  }
  float fs = (lane < K_) ? s + en[lane] : -1e30f;
  float best = -1e30f; int last = 0;
#pragma unroll
  for (int j = 0; j < K_; ++j) {
    float v = __shfl(fs, j);
    if (v > best) { best = v; last = j; }
  }
  __syncthreads();                            // hist visible to lane 0
  if (lane == 0) {
    int tag = last;
    tags[b * T_ + len - 1] = tag;
    for (int t = len - 2; t >= 0; --t) {
      tag = hist[t * 16 + tag];
      tags[b * T_ + t] = tag;
    }
  }
  for (int t = len + lane; t < T_; t += 64) tags[b * T_ + t] = 0;
}

// ---------------------------------------------------------------------------
extern "C" void kernel_launch(void* const* d_in, const int* in_sizes, int n_in,
                              void* d_out, int out_size, void* d_ws, size_t ws_size,
                              hipStream_t stream)
{
  const int*   sent  = (const int*)d_in[0];
  const int*   lens  = (const int*)d_in[1];
  const float* embed = (const float*)d_in[2];
  const float* Wif   = (const float*)d_in[3];
  const float* Whf   = (const float*)d_in[4];
  const float* bif   = (const float*)d_in[5];
  const float* bhf   = (const float*)d_in[6];
  const float* Wib   = (const float*)d_in[7];
  const float* Whb   = (const float*)d_in[8];
  const float* bib   = (const float*)d_in[9];
  const float* bhb   = (const float*)d_in[10];
  const float* Wout  = (const float*)d_in[11];
  const float* bout  = (const float*)d_in[12];
  const float* stt   = (const float*)d_in[13];
  const float* ent   = (const float*)d_in[14];
  const float* trans = (const float*)d_in[15];
  int* tags = (int*)d_out;

  // workspace layout (floats): hs | em | state_h | state_c | proj(chunked)
  float* ws   = (float*)d_ws;
  float* hs   = ws;                                  // B*T*256   (67.1 MB)
  float* em   = hs + (size_t)B_ * T_ * 256;          // B*T*9     ( 2.4 MB)
  float* sh   = em + (size_t)B_ * T_ * K_;           // 2*B*H carry h
  float* sc   = sh + (size_t)2 * B_ * H_;            // 2*B*H carry c
  float* proj = sc + (size_t)2 * B_ * H_;
  const size_t fixed_bytes = (size_t)(proj - ws) * sizeof(float);

  // largest time-chunk whose proj buffer fits the workspace (floor at 64)
  int Tc = 512, tcshift = 9;
  while (Tc > 64 && fixed_bytes + (size_t)B_ * Tc * 1024 * sizeof(float) > ws_size) {
    Tc >>= 1; tcshift--;
  }

  const int nch = T_ / Tc;
  for (int c2 = 0; c2 < nch; ++c2) {
    const int t0f = c2 * Tc;
    dim3 g1(16, (B_ * Tc) >> 6);
    hipLaunchKernelGGL(proj_mfma, g1, dim3(256), 0, stream,
                       sent, embed, Wif, Wib, bif, bhf, bib, bhb,
                       proj, t0f, Tc, tcshift);
    dim3 g2(2, B_);
    hipLaunchKernelGGL(lstm_chunk2, g2, dim3(256), 0, stream,
                       proj, Whf, Whb, lens, hs, sh, sc, t0f, Tc, (int)(c2 == 0));
  }
  hipLaunchKernelGGL(emis_kernel, dim3((B_ * T_) / 256), dim3(256), 0, stream,
                     hs, Wout, bout, em);
  hipLaunchKernelGGL(viterbi_kernel, dim3(B_), dim3(64), 0, stream,
                     em, lens, stt, ent, trans, tags);
}